// Round 23
// baseline (162.014 us; speedup 1.0000x reference)
//
#include <hip/hip_runtime.h>
#include <float.h>

typedef _Float16 half8 __attribute__((ext_vector_type(8)));
typedef float    f32x4 __attribute__((ext_vector_type(4)));
typedef unsigned long long u64;

#define N_ROWS   65536
#define DIM      256
#define KCODES   1024
#define VQ_BETA  0.25
#define MARGIN   1.5f   // hard bound: need > 2*eps = 0.82 (eps <= 2^-10*||x||*||e|| = 0.41)
#define HCAP     640

// ---------------------------------------------------------------------------
// Order-preserving float->uint key (monotone, handles negatives)
__device__ __forceinline__ unsigned fkey(float f) {
    const unsigned u = __float_as_uint(f);
    return u ^ (0x80000000u | (unsigned)((int)u >> 31));
}

// ---------------------------------------------------------------------------
// Kernel 0 (FUSED prologue): one launch, three independent block ranges.
__global__ __launch_bounds__(256) void fused_prep(
        const float* __restrict__ E, float* __restrict__ Et,
        _Float16* __restrict__ Efb, float* __restrict__ enorm)
{
    const int b = blockIdx.x;
    if (b < 256) {
        __shared__ float t[32][33];
        const int kt = (b & 31) * 32;
        const int dt = (b >> 5) * 32;
        const int lx = threadIdx.x & 31;
        const int ly = threadIdx.x >> 5;
#pragma unroll
        for (int i = 0; i < 4; ++i) {
            int d = dt + ly + i * 8;
            t[ly + i * 8][lx] = E[(size_t)d * KCODES + kt + lx];
        }
        __syncthreads();
#pragma unroll
        for (int i = 0; i < 4; ++i) {
            int k = kt + ly + i * 8;
            Et[(size_t)k * DIM + dt + lx] = t[lx][ly + i * 8];
        }
    } else if (b < 384) {
        const int fid = (b - 256) * 256 + threadIdx.x;   // 0..32767
        const int lhi   = fid & 3;
        const int llo   = (fid >> 2) & 15;
        const int nt    = (fid >> 6) & 3;
        const int w     = (fid >> 8) & 3;
        const int slice = fid >> 10;                     // 0..31
        const int chunk = slice >> 3, ks = slice & 7;
        const int code  = chunk * 256 + w * 64 + nt * 16 + llo;
        const int dbase = ks * 32 + lhi * 8;
        half8 h;
#pragma unroll
        for (int j = 0; j < 8; ++j)
            h[j] = (_Float16)E[(size_t)(dbase + j) * KCODES + code];
        *reinterpret_cast<half8*>(Efb + (size_t)fid * 8) = h;
    } else {
        const int k = (b - 384) * 256 + threadIdx.x;
        float s = 0.f;
#pragma unroll 4
        for (int d = 0; d < DIM; ++d) {
            float v = E[(size_t)d * KCODES + k];
            s = fmaf(v, v, s);
        }
        enorm[k] = s;
    }
}

// ---------------------------------------------------------------------------
// Opaque async global load: compiler cannot re-roll or JIT-serialize it
// (rounds 12/14: source-level prefetch was canonicalized away, VGPR stuck
// at 64). Completion is managed MANUALLY via counted s_waitcnt vmcnt(N).
__device__ __forceinline__ void gload16(half8 &dst, const _Float16* p) {
    asm volatile("global_load_dwordx4 %0, %1, off"
                 : "=v"(dst) : "v"(p) : "memory");
}
// Counted wait + scheduler fence (rule #18: sched_barrier stops register-only
// MFMA from being hoisted past the inline-asm waitcnt).
#define WAITV(N) do { asm volatile("s_waitcnt vmcnt(" #N ")" ::: "memory"); \
                      __builtin_amdgcn_sched_barrier(0); } while (0)

__device__ __forceinline__ void load_af(const char* AhB, int ks, int llo, int lhi,
                                        int aswz, half8 (&af)[4]) {
#pragma unroll
    for (int mt = 0; mt < 4; ++mt) {
        const int addr = ((mt * 16 + llo) * 512 + (ks * 4 + lhi) * 16) ^ aswz;
        af[mt] = *reinterpret_cast<const half8*>(AhB + addr);
    }
}
__device__ __forceinline__ void mfma2(const half8 (&af)[4], const half8 (&b)[2],
                                      f32x4 (&acc)[4][2]) {
#pragma unroll
    for (int mt = 0; mt < 4; ++mt) {
        acc[mt][0] = __builtin_amdgcn_mfma_f32_16x16x32_f16(af[mt], b[0], acc[mt][0], 0, 0, 0);
        acc[mt][1] = __builtin_amdgcn_mfma_f32_16x16x32_f16(af[mt], b[1], acc[mt][1], 0, 0, 0);
    }
}

// One 64-row x 32-code x K=256 accumulation per wave. B via ASM loads with a
// TRUE 4-pair-deep rotation; consumption gated by literal counted vmcnt
// (6,6,6,6,6,4,2,0 -- outstanding-after-pair-ks given 8-load prologue and
// one-pair-per-step reissue). ds_read af issued BEFORE the wait so LDS
// latency overlaps the vmcnt wait. Each chunk drains to vmcnt(0) at ks=7,
// so the per-chunk barrier's full drain costs nothing and counting restarts
// clean every chunk. INVARIANT: no other VMEM in the K-loop (e2v comes from
// LDS enorm_s; filter/reduce are DS-domain).
#define KS_STEP(ks, W) do { \
    load_af(AhB, ks, llo, lhi, aswz, af); \
    WAITV(W); \
    mfma2(af, bq[(ks) & 3], acc); \
    if ((ks) < 4) { \
        gload16(bq[(ks) & 3][0], ebase + (size_t)((ks) + 4) * 8192); \
        gload16(bq[(ks) & 3][1], ebase + (size_t)((ks) + 4) * 8192 + 512); \
    } \
} while (0)

__device__ __forceinline__ void mfma_chunk(
        const _Float16* __restrict__ ebase, const char* AhB,
        int llo, int lhi, int aswz, f32x4 (&acc)[4][2]) {
    half8 bq[4][2], af[4];
#pragma unroll
    for (int k = 0; k < 4; ++k) {
        gload16(bq[k][0], ebase + (size_t)k * 8192);
        gload16(bq[k][1], ebase + (size_t)k * 8192 + 512);
    }
    KS_STEP(0, 6); KS_STEP(1, 6); KS_STEP(2, 6); KS_STEP(3, 6);
    KS_STEP(4, 6); KS_STEP(5, 4); KS_STEP(6, 2); KS_STEP(7, 0);
}

// ---------------------------------------------------------------------------
// Kernel 1: SINGLE-pass pruned argmin (running cutoff) + fused epilogue.
// Round-22 structure (measured 159.1us total, absmax 0) with ONE change:
// the K-loop's B-path is the forced ISA-level 4-deep pipeline above, and
// enorm is staged to LDS so counted vmcnt sees only our loads.
__global__ __launch_bounds__(512, 4) void vq_mfma(
        const float* __restrict__ X, const _Float16* __restrict__ Efb,
        const float* __restrict__ enorm, const float* __restrict__ Et,
        float* __restrict__ outidx, float* __restrict__ outq,
        float* __restrict__ partials)
{
    __shared__ _Float16 Ah[64 * 256];     // 32 KB, swizzled
    __shared__ float    enorm_s[KCODES];  // 4 KB (K-loop reads e2 from LDS)
    __shared__ float    bminw[8][64];     // 2 KB
    __shared__ float    cutoff_s[64];
    __shared__ float    rmin_s[64];
    __shared__ u64      minpk[64];        // packed (fkey(dd)<<10)|code
    __shared__ int      rowbad[64];
    __shared__ int      hits[HCAP];       // 2.5 KB
    __shared__ float    xs[DIM];          // 1 KB (fallback row cache)
    __shared__ float    wlsum[8];
    __shared__ unsigned hitcnt;

    const int tid = threadIdx.x;
    const int rowbase = blockIdx.x * 64;

    if (tid == 0) hitcnt = 0;
    if (tid < 64) {
        minpk[tid] = 0xFFFFFFFFFFFFFFFFULL;
        rmin_s[tid] = FLT_MAX;
        rowbad[tid] = 0;
    }
    for (int i = tid; i < KCODES; i += 512) enorm_s[i] = enorm[i];

    // ---- stage A tile: fp32 -> fp16 swizzled LDS (8 threads/row) ----
    {
        const int row = tid >> 3;
#pragma unroll
        for (int i = 0; i < 4; ++i) {
            const int g = (tid & 7) + 8 * i;        // 16B-chunk index 0..31
            const float* src = X + (size_t)(rowbase + row) * DIM + g * 8;
            float4 a = *reinterpret_cast<const float4*>(src);
            float4 b = *reinterpret_cast<const float4*>(src + 4);
            half8 h;
            h[0] = (_Float16)a.x; h[1] = (_Float16)a.y;
            h[2] = (_Float16)a.z; h[3] = (_Float16)a.w;
            h[4] = (_Float16)b.x; h[5] = (_Float16)b.y;
            h[6] = (_Float16)b.z; h[7] = (_Float16)b.w;
            const int addr = (row * 512 + g * 16) ^ ((row & 7) << 4);
            *reinterpret_cast<half8*>(reinterpret_cast<char*>(Ah) + addr) = h;
        }
    }
    __syncthreads();   // drains vmcnt to 0 -> clean counting for chunk 0

    const int w    = tid >> 6;            // 0..7
    const int lane = tid & 63;
    const int lhi  = lane >> 4, llo = lane & 15;
    const int aswz = (llo & 7) << 4;
    const int lane_off8 = (llo * 4 + lhi) * 8;
    const char* AhB = reinterpret_cast<const char*>(Ah);

    // ======================= SINGLE PASS over 4 chunks =======================
    for (int chunk = 0; chunk < 4; ++chunk) {
        f32x4 acc[4][2];
#pragma unroll
        for (int mt = 0; mt < 4; ++mt)
#pragma unroll
            for (int nt = 0; nt < 2; ++nt) acc[mt][nt] = (f32x4){0.f, 0.f, 0.f, 0.f};

        const _Float16* ebase = Efb + (size_t)chunk * 65536 + w * 1024 + lane_off8;
        mfma_chunk(ebase, AhB, llo, lhi, aswz, acc);

        // ds in place (acc := e2 - 2*S~), per-slot min over nt; e2 from LDS
        float e2v[2];
#pragma unroll
        for (int nt = 0; nt < 2; ++nt)
            e2v[nt] = enorm_s[chunk * 256 + w * 32 + nt * 16 + llo];

        float mloc[16];
#pragma unroll
        for (int mt = 0; mt < 4; ++mt)
#pragma unroll
            for (int q = 0; q < 4; ++q) {
                float m = FLT_MAX;
#pragma unroll
                for (int nt = 0; nt < 2; ++nt) {
                    const float ds = fmaf(-2.0f, acc[mt][nt][q], e2v[nt]);
                    acc[mt][nt][q] = ds;
                    m = fminf(m, ds);
                }
                mloc[mt * 4 + q] = m;
            }
        // min across the 16 llo lanes (same rows)
#pragma unroll
        for (int m = 1; m < 16; m <<= 1)
#pragma unroll
            for (int sl = 0; sl < 16; ++sl)
                mloc[sl] = fminf(mloc[sl], __shfl_xor(mloc[sl], m, 64));
        if (llo == 0) {
#pragma unroll
            for (int mt = 0; mt < 4; ++mt)
#pragma unroll
                for (int q = 0; q < 4; ++q)
                    bminw[w][mt * 16 + lhi * 4 + q] = mloc[mt * 4 + q];
        }
        __syncthreads();
        if (tid < 64) {
            float r = bminw[0][tid];
#pragma unroll
            for (int ww = 1; ww < 8; ++ww) r = fminf(r, bminw[ww][tid]);
            r = fminf(rmin_s[tid], r);
            rmin_s[tid]   = r;
            cutoff_s[tid] = r + MARGIN;
        }
        __syncthreads();

        // filter this chunk's ds against the running cutoff, append candidates
#pragma unroll
        for (int mt = 0; mt < 4; ++mt)
#pragma unroll
            for (int q = 0; q < 4; ++q) {
                const int row = mt * 16 + lhi * 4 + q;
                const float cut = cutoff_s[row];
#pragma unroll
                for (int nt = 0; nt < 2; ++nt) {
                    if (acc[mt][nt][q] < cut) {
                        const unsigned p = atomicAdd(&hitcnt, 1u);
                        if (p < HCAP)
                            hits[p] = (row << 10) |
                                      (chunk * 256 + w * 32 + nt * 16 + llo);
                        else
                            rowbad[row] = 1;     // row-targeted fallback later
                    }
                }
            }
    }
    __syncthreads();

    // ============================ EXACT RESCORE ============================
    // One thread per candidate; SEQUENTIAL d=0..255 fma chains (np-identical).
    // Winner: one packed 64-bit atomicMin (dd primary, lowest code on ties).
    const int nh = (int)(hitcnt < HCAP ? hitcnt : (unsigned)HCAP);

    for (int hi = tid; hi < nh; hi += 512) {
        const int pk = hits[hi];
        const int rl = pk >> 10, code = pk & 1023;
        const float* xr = X  + (size_t)(rowbase + rl) * DIM;
        const float* er = Et + (size_t)code * DIM;
        float p = 0.f, x2 = 0.f;
#pragma unroll
        for (int j = 0; j < 64; ++j) {          // ascending d, fixed order
            float4 xv = *reinterpret_cast<const float4*>(xr + j * 4);
            float4 ev = *reinterpret_cast<const float4*>(er + j * 4);
            x2 = fmaf(xv.x, xv.x, x2); x2 = fmaf(xv.y, xv.y, x2);
            x2 = fmaf(xv.z, xv.z, x2); x2 = fmaf(xv.w, xv.w, x2);
            p  = fmaf(xv.x, ev.x, p);  p  = fmaf(xv.y, ev.y, p);
            p  = fmaf(xv.z, ev.z, p);  p  = fmaf(xv.w, ev.w, p);
        }
        const float dd = (x2 - 2.0f * p) + enorm_s[code];
        atomicMin(&minpk[rl], ((u64)fkey(dd) << 10) | (unsigned)code);
    }
    __syncthreads();

    // ------ per-row fallback for rows whose candidates overflowed HCAP ------
    // (statistically near-never; bitwise-identical sequential chains so merged
    //  minima are consistent with the rescore path). Barriers block-uniform.
    for (int r = 0; r < 64; ++r) {
        if (!rowbad[r]) continue;             // uniform branch (LDS value)
        if (tid < 256) xs[tid] = X[(size_t)(rowbase + r) * DIM + tid];
        __syncthreads();
        if (tid < 256) {
            float x2 = 0.f;
            for (int d = 0; d < DIM; ++d) x2 = fmaf(xs[d], xs[d], x2);
            float a0 = 0.f, a1 = 0.f, a2 = 0.f, a3 = 0.f;
            const float* e0 = Et + (size_t)(tid      ) * DIM;
            const float* e1 = Et + (size_t)(tid + 256) * DIM;
            const float* e2p = Et + (size_t)(tid + 512) * DIM;
            const float* e3 = Et + (size_t)(tid + 768) * DIM;
            for (int d = 0; d < DIM; ++d) {
                const float xv = xs[d];
                a0 = fmaf(xv, e0[d], a0);
                a1 = fmaf(xv, e1[d], a1);
                a2 = fmaf(xv, e2p[d], a2);
                a3 = fmaf(xv, e3[d], a3);
            }
            const float d0 = (x2 - 2.0f * a0) + enorm_s[tid];
            const float d1 = (x2 - 2.0f * a1) + enorm_s[tid + 256];
            const float d2 = (x2 - 2.0f * a2) + enorm_s[tid + 512];
            const float d3 = (x2 - 2.0f * a3) + enorm_s[tid + 768];
            atomicMin(&minpk[r], ((u64)fkey(d0) << 10) | (unsigned)tid);
            atomicMin(&minpk[r], ((u64)fkey(d1) << 10) | (unsigned)(tid + 256));
            atomicMin(&minpk[r], ((u64)fkey(d2) << 10) | (unsigned)(tid + 512));
            atomicMin(&minpk[r], ((u64)fkey(d3) << 10) | (unsigned)(tid + 768));
        }
        __syncthreads();
    }

    // ======================= FUSED EPILOGUE (L2-hot) =======================
    float lsum = 0.f;
    {
        const int row  = tid >> 3;       // 64 rows, 8 threads/row
        const int part = tid & 7;
        const int cw   = (int)(minpk[row] & 1023ULL);
        const float* xrow = X  + (size_t)(rowbase + row) * DIM;
        const float* ew   = Et + (size_t)cw * DIM;
        float* oq = outq + (size_t)(rowbase + row) * DIM;
        if (part == 0) outidx[rowbase + row] = (float)cw;

#pragma unroll
        for (int j = 0; j < 8; ++j) {
            const int d0 = j * 32 + part * 4;
            float4 q = *reinterpret_cast<const float4*>(ew + d0);
            float4 x = *reinterpret_cast<const float4*>(xrow + d0);
            float4 o;
            o.x = x.x + (q.x - x.x);
            o.y = x.y + (q.y - x.y);
            o.z = x.z + (q.z - x.z);
            o.w = x.w + (q.w - x.w);
            *reinterpret_cast<float4*>(oq + d0) = o;
            float dx;
            dx = q.x - x.x; lsum = fmaf(dx, dx, lsum);
            dx = q.y - x.y; lsum = fmaf(dx, dx, lsum);
            dx = q.z - x.z; lsum = fmaf(dx, dx, lsum);
            dx = q.w - x.w; lsum = fmaf(dx, dx, lsum);
        }
    }
    // in-wave reduce, then 8 wave-partials -> one block partial
#pragma unroll
    for (int m = 1; m < 64; m <<= 1) lsum += __shfl_xor(lsum, m, 64);
    if (lane == 0) wlsum[w] = lsum;
    __syncthreads();
    if (tid == 0) {
        float s = wlsum[0];
#pragma unroll
        for (int ww = 1; ww < 8; ++ww) s += wlsum[ww];
        partials[blockIdx.x] = s;
    }
}

// ---------------------------------------------------------------------------
__global__ void loss_final(const float* __restrict__ partials, float* __restrict__ out) {
    __shared__ double sd[256];
    const int tid = threadIdx.x;
    double s = 0.0;
    for (int i = tid; i < 1024; i += 256) s += (double)partials[i];
    sd[tid] = s;
    __syncthreads();
    for (int k = 128; k > 0; k >>= 1) {
        if (tid < k) sd[tid] += sd[tid + k];
        __syncthreads();
    }
    if (tid == 0) out[0] = (float)(VQ_BETA * sd[0] / (double)((size_t)N_ROWS * DIM));
}

// ---------------------------------------------------------------------------
extern "C" void kernel_launch(void* const* d_in, const int* in_sizes, int n_in,
                              void* d_out, int out_size, void* d_ws, size_t ws_size,
                              hipStream_t stream) {
    const float* X = (const float*)d_in[0];   // [65536][256]
    const float* E = (const float*)d_in[1];   // [256][1024]

    float* outq    = (float*)d_out;                       // [16777216]
    float* outloss = outq + (size_t)N_ROWS * DIM;         // [1]
    float* outidx  = outloss + 1;                         // [65536] (float-coded)

    float*    Et       = (float*)d_ws;                    // 1 MB
    _Float16* Efb      = (_Float16*)(Et + 262144);        // 512 KB
    float*    enormw   = (float*)(Efb + 262144);          // 4 KB
    float*    partials = enormw + KCODES;                 // 4 KB (1024)

    fused_prep <<<388,         256, 0, stream>>>(E, Et, Efb, enormw);
    vq_mfma    <<<N_ROWS / 64, 512, 0, stream>>>(X, Efb, enormw, Et,
                                                 outidx, outq, partials);
    loss_final <<<1,           256, 0, stream>>>(partials, outloss);
}

// Round 24
// 158.894 us; speedup vs baseline: 1.0196x; 1.0196x over previous
//
#include <hip/hip_runtime.h>
#include <float.h>

typedef _Float16 half8 __attribute__((ext_vector_type(8)));
typedef float    f32x4 __attribute__((ext_vector_type(4)));
typedef unsigned long long u64;

#define N_ROWS   65536
#define DIM      256
#define KCODES   1024
#define VQ_BETA  0.25
#define MARGIN   1.5f   // hard bound: need > 2*eps = 0.82 (eps <= 2^-10*||x||*||e|| = 0.41)
#define HCAP     640

// ---------------------------------------------------------------------------
// Order-preserving float->uint key (monotone, handles negatives)
__device__ __forceinline__ unsigned fkey(float f) {
    const unsigned u = __float_as_uint(f);
    return u ^ (0x80000000u | (unsigned)((int)u >> 31));
}

// ---------------------------------------------------------------------------
// Kernel 0 (FUSED prologue): one launch, three independent block ranges.
//   blocks [0,256):   transpose E -> Et  (Et[k][d] = E[d][k])
//   blocks [256,384): Efb fp16 B-fragments DIRECT from E (64B-coalesced gather)
//   blocks [384,388): enorm[k] = sum_d E[d][k]^2 (sequential d order)
__global__ __launch_bounds__(256) void fused_prep(
        const float* __restrict__ E, float* __restrict__ Et,
        _Float16* __restrict__ Efb, float* __restrict__ enorm)
{
    const int b = blockIdx.x;
    if (b < 256) {
        __shared__ float t[32][33];
        const int kt = (b & 31) * 32;
        const int dt = (b >> 5) * 32;
        const int lx = threadIdx.x & 31;
        const int ly = threadIdx.x >> 5;
#pragma unroll
        for (int i = 0; i < 4; ++i) {
            int d = dt + ly + i * 8;
            t[ly + i * 8][lx] = E[(size_t)d * KCODES + kt + lx];
        }
        __syncthreads();
#pragma unroll
        for (int i = 0; i < 4; ++i) {
            int k = kt + ly + i * 8;
            Et[(size_t)k * DIM + dt + lx] = t[lx][ly + i * 8];
        }
    } else if (b < 384) {
        // Efb[fid][j] = Et[code][ks*32+lhi*8+j] = E[(ks*32+lhi*8+j)*1024+code]
        const int fid = (b - 256) * 256 + threadIdx.x;   // 0..32767
        const int lhi   = fid & 3;
        const int llo   = (fid >> 2) & 15;
        const int nt    = (fid >> 6) & 3;
        const int w     = (fid >> 8) & 3;
        const int slice = fid >> 10;                     // 0..31
        const int chunk = slice >> 3, ks = slice & 7;
        const int code  = chunk * 256 + w * 64 + nt * 16 + llo;
        const int dbase = ks * 32 + lhi * 8;
        half8 h;
#pragma unroll
        for (int j = 0; j < 8; ++j)
            h[j] = (_Float16)E[(size_t)(dbase + j) * KCODES + code];
        *reinterpret_cast<half8*>(Efb + (size_t)fid * 8) = h;
    } else {
        const int k = (b - 384) * 256 + threadIdx.x;
        float s = 0.f;
#pragma unroll 4
        for (int d = 0; d < DIM; ++d) {
            float v = E[(size_t)d * KCODES + k];
            s = fmaf(v, v, s);
        }
        enorm[k] = s;
    }
}

// ---------------------------------------------------------------------------
__device__ __forceinline__ void load_bf2(const _Float16* __restrict__ eb,
                                         half8 (&bf)[2]) {
    bf[0] = *reinterpret_cast<const half8*>(eb);
    bf[1] = *reinterpret_cast<const half8*>(eb + 512);
}
__device__ __forceinline__ void load_af(const char* AhB, int ks, int llo, int lhi,
                                        int aswz, half8 (&af)[4]) {
#pragma unroll
    for (int mt = 0; mt < 4; ++mt) {
        const int addr = ((mt * 16 + llo) * 512 + (ks * 4 + lhi) * 16) ^ aswz;
        af[mt] = *reinterpret_cast<const half8*>(AhB + addr);
    }
}
// One 64-row x 32-code x K=256 accumulation per wave; B direct from global
// (L2-hot) with 4-deep prefetch rotation; A from swizzled LDS; NO barriers.
__device__ __forceinline__ void mfma_chunk(
        const _Float16* __restrict__ ebase, const char* AhB,
        int llo, int lhi, int aswz, f32x4 (&acc)[4][2]) {
    half8 bf[4][2], af[4];
#pragma unroll
    for (int k = 0; k < 4; ++k) load_bf2(ebase + (size_t)k * 8192, bf[k]);
#pragma unroll
    for (int ks = 0; ks < 8; ++ks) {
        const int b = ks & 3;
        const half8 b0 = bf[b][0], b1 = bf[b][1];
        if (ks < 4) load_bf2(ebase + (size_t)(ks + 4) * 8192, bf[b]);
        load_af(AhB, ks, llo, lhi, aswz, af);
#pragma unroll
        for (int mt = 0; mt < 4; ++mt) {
            acc[mt][0] = __builtin_amdgcn_mfma_f32_16x16x32_f16(af[mt], b0, acc[mt][0], 0, 0, 0);
            acc[mt][1] = __builtin_amdgcn_mfma_f32_16x16x32_f16(af[mt], b1, acc[mt][1], 0, 0, 0);
        }
    }
}

// ---------------------------------------------------------------------------
// Kernel 1: SINGLE-pass pruned argmin (running cutoff) + fused epilogue.
// SESSION-FINAL configuration (rounds 20/22, twice-measured 159.3/159.05us
// total, absmax 0): 512 thr = 8 waves, 64 rows/block; per-chunk running
// cutoff (2 barriers/chunk); packed 64-bit LDS atomicMin rescore (np
// first-min tie-break); fused L2-hot gather + STE write + loss partial.
// Complete ledger: twelve structural variants (occupancy x2, source-level
// prefetch x2, ISA-forced counted-vmcnt pipeline, A-pipelining, barrier
// removal x3, LDS trims x2, r8 geometry, epilogue shedding, loss fusion)
// all pinned this kernel at 141-153us with all pipes <20% and occupancy
// register-governed at ~41% -- this decomposition's established floor.
__global__ __launch_bounds__(512, 4) void vq_mfma(
        const float* __restrict__ X, const _Float16* __restrict__ Efb,
        const float* __restrict__ enorm, const float* __restrict__ Et,
        float* __restrict__ outidx, float* __restrict__ outq,
        float* __restrict__ partials)
{
    __shared__ _Float16 Ah[64 * 256];     // 32 KB, swizzled
    __shared__ float    bminw[8][64];     // 2 KB
    __shared__ float    cutoff_s[64];
    __shared__ float    rmin_s[64];
    __shared__ u64      minpk[64];        // packed (fkey(dd)<<10)|code
    __shared__ int      rowbad[64];
    __shared__ int      hits[HCAP];       // 2.5 KB
    __shared__ float    xs[DIM];          // 1 KB (fallback row cache)
    __shared__ float    wlsum[8];
    __shared__ unsigned hitcnt;

    const int tid = threadIdx.x;
    const int rowbase = blockIdx.x * 64;

    if (tid == 0) hitcnt = 0;
    if (tid < 64) {
        minpk[tid] = 0xFFFFFFFFFFFFFFFFULL;
        rmin_s[tid] = FLT_MAX;
        rowbad[tid] = 0;
    }

    // ---- stage A tile: fp32 -> fp16 swizzled LDS (8 threads/row) ----
    {
        const int row = tid >> 3;
#pragma unroll
        for (int i = 0; i < 4; ++i) {
            const int g = (tid & 7) + 8 * i;        // 16B-chunk index 0..31
            const float* src = X + (size_t)(rowbase + row) * DIM + g * 8;
            float4 a = *reinterpret_cast<const float4*>(src);
            float4 b = *reinterpret_cast<const float4*>(src + 4);
            half8 h;
            h[0] = (_Float16)a.x; h[1] = (_Float16)a.y;
            h[2] = (_Float16)a.z; h[3] = (_Float16)a.w;
            h[4] = (_Float16)b.x; h[5] = (_Float16)b.y;
            h[6] = (_Float16)b.z; h[7] = (_Float16)b.w;
            const int addr = (row * 512 + g * 16) ^ ((row & 7) << 4);
            *reinterpret_cast<half8*>(reinterpret_cast<char*>(Ah) + addr) = h;
        }
    }
    __syncthreads();

    const int w    = tid >> 6;            // 0..7
    const int lane = tid & 63;
    const int lhi  = lane >> 4, llo = lane & 15;
    const int aswz = (llo & 7) << 4;
    const int lane_off8 = (llo * 4 + lhi) * 8;
    const char* AhB = reinterpret_cast<const char*>(Ah);

    // ======================= SINGLE PASS over 4 chunks =======================
    for (int chunk = 0; chunk < 4; ++chunk) {
        f32x4 acc[4][2];
#pragma unroll
        for (int mt = 0; mt < 4; ++mt)
#pragma unroll
            for (int nt = 0; nt < 2; ++nt) acc[mt][nt] = (f32x4){0.f, 0.f, 0.f, 0.f};

        const _Float16* ebase = Efb + (size_t)chunk * 65536 + w * 1024 + lane_off8;
        mfma_chunk(ebase, AhB, llo, lhi, aswz, acc);

        // ds in place (acc := e2 - 2*S~), per-slot min over nt
        float e2v[2];
#pragma unroll
        for (int nt = 0; nt < 2; ++nt)
            e2v[nt] = enorm[chunk * 256 + w * 32 + nt * 16 + llo];

        float mloc[16];
#pragma unroll
        for (int mt = 0; mt < 4; ++mt)
#pragma unroll
            for (int q = 0; q < 4; ++q) {
                float m = FLT_MAX;
#pragma unroll
                for (int nt = 0; nt < 2; ++nt) {
                    const float ds = fmaf(-2.0f, acc[mt][nt][q], e2v[nt]);
                    acc[mt][nt][q] = ds;
                    m = fminf(m, ds);
                }
                mloc[mt * 4 + q] = m;
            }
        // min across the 16 llo lanes (same rows)
#pragma unroll
        for (int m = 1; m < 16; m <<= 1)
#pragma unroll
            for (int sl = 0; sl < 16; ++sl)
                mloc[sl] = fminf(mloc[sl], __shfl_xor(mloc[sl], m, 64));
        if (llo == 0) {
#pragma unroll
            for (int mt = 0; mt < 4; ++mt)
#pragma unroll
                for (int q = 0; q < 4; ++q)
                    bminw[w][mt * 16 + lhi * 4 + q] = mloc[mt * 4 + q];
        }
        __syncthreads();
        if (tid < 64) {
            float r = bminw[0][tid];
#pragma unroll
            for (int ww = 1; ww < 8; ++ww) r = fminf(r, bminw[ww][tid]);
            r = fminf(rmin_s[tid], r);
            rmin_s[tid]   = r;
            cutoff_s[tid] = r + MARGIN;
        }
        __syncthreads();

        // filter this chunk's ds against the running cutoff, append candidates
#pragma unroll
        for (int mt = 0; mt < 4; ++mt)
#pragma unroll
            for (int q = 0; q < 4; ++q) {
                const int row = mt * 16 + lhi * 4 + q;
                const float cut = cutoff_s[row];
#pragma unroll
                for (int nt = 0; nt < 2; ++nt) {
                    if (acc[mt][nt][q] < cut) {
                        const unsigned p = atomicAdd(&hitcnt, 1u);
                        if (p < HCAP)
                            hits[p] = (row << 10) |
                                      (chunk * 256 + w * 32 + nt * 16 + llo);
                        else
                            rowbad[row] = 1;     // row-targeted fallback later
                    }
                }
            }
    }
    __syncthreads();

    // ============================ EXACT RESCORE ============================
    // One thread per candidate; SEQUENTIAL d=0..255 fma chains (np-identical).
    // Winner: one packed 64-bit atomicMin (dd primary, lowest code on ties).
    const int nh = (int)(hitcnt < HCAP ? hitcnt : (unsigned)HCAP);

    for (int hi = tid; hi < nh; hi += 512) {
        const int pk = hits[hi];
        const int rl = pk >> 10, code = pk & 1023;
        const float* xr = X  + (size_t)(rowbase + rl) * DIM;
        const float* er = Et + (size_t)code * DIM;
        float p = 0.f, x2 = 0.f;
#pragma unroll
        for (int j = 0; j < 64; ++j) {          // ascending d, fixed order
            float4 xv = *reinterpret_cast<const float4*>(xr + j * 4);
            float4 ev = *reinterpret_cast<const float4*>(er + j * 4);
            x2 = fmaf(xv.x, xv.x, x2); x2 = fmaf(xv.y, xv.y, x2);
            x2 = fmaf(xv.z, xv.z, x2); x2 = fmaf(xv.w, xv.w, x2);
            p  = fmaf(xv.x, ev.x, p);  p  = fmaf(xv.y, ev.y, p);
            p  = fmaf(xv.z, ev.z, p);  p  = fmaf(xv.w, ev.w, p);
        }
        const float dd = (x2 - 2.0f * p) + enorm[code];
        atomicMin(&minpk[rl], ((u64)fkey(dd) << 10) | (unsigned)code);
    }
    __syncthreads();

    // ------ per-row fallback for rows whose candidates overflowed HCAP ------
    // (statistically near-never; bitwise-identical sequential chains so merged
    //  minima are consistent with the rescore path). Barriers block-uniform.
    for (int r = 0; r < 64; ++r) {
        if (!rowbad[r]) continue;             // uniform branch (LDS value)
        if (tid < 256) xs[tid] = X[(size_t)(rowbase + r) * DIM + tid];
        __syncthreads();
        if (tid < 256) {
            float x2 = 0.f;
            for (int d = 0; d < DIM; ++d) x2 = fmaf(xs[d], xs[d], x2);
            float a0 = 0.f, a1 = 0.f, a2 = 0.f, a3 = 0.f;
            const float* e0 = Et + (size_t)(tid      ) * DIM;
            const float* e1 = Et + (size_t)(tid + 256) * DIM;
            const float* e2p = Et + (size_t)(tid + 512) * DIM;
            const float* e3 = Et + (size_t)(tid + 768) * DIM;
            for (int d = 0; d < DIM; ++d) {
                const float xv = xs[d];
                a0 = fmaf(xv, e0[d], a0);
                a1 = fmaf(xv, e1[d], a1);
                a2 = fmaf(xv, e2p[d], a2);
                a3 = fmaf(xv, e3[d], a3);
            }
            const float d0 = (x2 - 2.0f * a0) + enorm[tid];
            const float d1 = (x2 - 2.0f * a1) + enorm[tid + 256];
            const float d2 = (x2 - 2.0f * a2) + enorm[tid + 512];
            const float d3 = (x2 - 2.0f * a3) + enorm[tid + 768];
            atomicMin(&minpk[r], ((u64)fkey(d0) << 10) | (unsigned)tid);
            atomicMin(&minpk[r], ((u64)fkey(d1) << 10) | (unsigned)(tid + 256));
            atomicMin(&minpk[r], ((u64)fkey(d2) << 10) | (unsigned)(tid + 512));
            atomicMin(&minpk[r], ((u64)fkey(d3) << 10) | (unsigned)(tid + 768));
        }
        __syncthreads();
    }

    // ======================= FUSED EPILOGUE (L2-hot) =======================
    float lsum = 0.f;
    {
        const int row  = tid >> 3;       // 64 rows, 8 threads/row
        const int part = tid & 7;
        const int cw   = (int)(minpk[row] & 1023ULL);
        const float* xrow = X  + (size_t)(rowbase + row) * DIM;
        const float* ew   = Et + (size_t)cw * DIM;
        float* oq = outq + (size_t)(rowbase + row) * DIM;
        if (part == 0) outidx[rowbase + row] = (float)cw;

#pragma unroll
        for (int j = 0; j < 8; ++j) {
            const int d0 = j * 32 + part * 4;
            float4 q = *reinterpret_cast<const float4*>(ew + d0);
            float4 x = *reinterpret_cast<const float4*>(xrow + d0);
            float4 o;
            o.x = x.x + (q.x - x.x);
            o.y = x.y + (q.y - x.y);
            o.z = x.z + (q.z - x.z);
            o.w = x.w + (q.w - x.w);
            *reinterpret_cast<float4*>(oq + d0) = o;
            float dx;
            dx = q.x - x.x; lsum = fmaf(dx, dx, lsum);
            dx = q.y - x.y; lsum = fmaf(dx, dx, lsum);
            dx = q.z - x.z; lsum = fmaf(dx, dx, lsum);
            dx = q.w - x.w; lsum = fmaf(dx, dx, lsum);
        }
    }
    // in-wave reduce, then 8 wave-partials -> one block partial
#pragma unroll
    for (int m = 1; m < 64; m <<= 1) lsum += __shfl_xor(lsum, m, 64);
    if (lane == 0) wlsum[w] = lsum;
    __syncthreads();
    if (tid == 0) {
        float s = wlsum[0];
#pragma unroll
        for (int ww = 1; ww < 8; ++ww) s += wlsum[ww];
        partials[blockIdx.x] = s;
    }
}

// ---------------------------------------------------------------------------
__global__ void loss_final(const float* __restrict__ partials, float* __restrict__ out) {
    __shared__ double sd[256];
    const int tid = threadIdx.x;
    double s = 0.0;
    for (int i = tid; i < 1024; i += 256) s += (double)partials[i];
    sd[tid] = s;
    __syncthreads();
    for (int k = 128; k > 0; k >>= 1) {
        if (tid < k) sd[tid] += sd[tid + k];
        __syncthreads();
    }
    if (tid == 0) out[0] = (float)(VQ_BETA * sd[0] / (double)((size_t)N_ROWS * DIM));
}

// ---------------------------------------------------------------------------
extern "C" void kernel_launch(void* const* d_in, const int* in_sizes, int n_in,
                              void* d_out, int out_size, void* d_ws, size_t ws_size,
                              hipStream_t stream) {
    const float* X = (const float*)d_in[0];   // [65536][256]
    const float* E = (const float*)d_in[1];   // [256][1024]

    float* outq    = (float*)d_out;                       // [16777216]
    float* outloss = outq + (size_t)N_ROWS * DIM;         // [1]
    float* outidx  = outloss + 1;                         // [65536] (float-coded)

    float*    Et       = (float*)d_ws;                    // 1 MB
    _Float16* Efb      = (_Float16*)(Et + 262144);        // 512 KB
    float*    enormw   = (float*)(Efb + 262144);          // 4 KB
    float*    partials = enormw + KCODES;                 // 4 KB (1024)

    fused_prep <<<388,         256, 0, stream>>>(E, Et, Efb, enormw);
    vq_mfma    <<<N_ROWS / 64, 512, 0, stream>>>(X, Efb, enormw, Et,
                                                 outidx, outq, partials);
    loss_final <<<1,           256, 0, stream>>>(partials, outloss);
}